// Round 2
// baseline (995.276 us; speedup 1.0000x reference)
//
#include <hip/hip_runtime.h>

#define NN 100000
#define NE 3200000
#define HD 64
#define SCAN_CHUNK 1024
#define NBLK ((NN + SCAN_CHUNK - 1) / SCAN_CHUNK)   // 98
#define NRANGE 8
#define RANGE_W (NN / NRANGE)                       // 12500

typedef int   v4i __attribute__((ext_vector_type(4)));
typedef float v4f __attribute__((ext_vector_type(4)));

__device__ __forceinline__ void fma4(float4& a, float s, const float4& b) {
    a.x = fmaf(s, b.x, a.x); a.y = fmaf(s, b.y, a.y);
    a.z = fmaf(s, b.z, a.z); a.w = fmaf(s, b.w, a.w);
}
__device__ __forceinline__ void add4(float4& a, const float4& b) {
    a.x += b.x; a.y += b.y; a.z += b.z; a.w += b.w;
}

// ---------------- degree histogram ----------------
__global__ void deg_kernel(const int* __restrict__ dst, int* __restrict__ deg) {
    int i = blockIdx.x * blockDim.x + threadIdx.x;
    if (i < NE / 4) {
        v4i d = __builtin_nontemporal_load((const v4i*)dst + i);
        atomicAdd(&deg[d.x], 1); atomicAdd(&deg[d.y], 1);
        atomicAdd(&deg[d.z], 1); atomicAdd(&deg[d.w], 1);
    }
}

__global__ void dinv_kernel(const int* __restrict__ deg, float* __restrict__ dinv) {
    int i = blockIdx.x * blockDim.x + threadIdx.x;
    if (i < NN) dinv[i] = 1.0f / sqrtf((float)(deg[i] + 1)); // +1 self-loop
}

// ---------------- prefix scan (3 kernels) ----------------
__global__ void block_sum_kernel(const int* __restrict__ deg, int* __restrict__ bsum) {
    __shared__ int red[256];
    int b = blockIdx.x, t = threadIdx.x;
    int base = b * SCAN_CHUNK + t * 4;
    int s = 0;
    #pragma unroll
    for (int i = 0; i < 4; i++) { int g = base + i; if (g < NN) s += deg[g]; }
    red[t] = s; __syncthreads();
    for (int off = 128; off > 0; off >>= 1) {
        if (t < off) red[t] += red[t + off];
        __syncthreads();
    }
    if (t == 0) bsum[b] = red[0];
}

// parallel 128-thread scan over NBLK (=98) block sums
__global__ void scan_bsum_kernel(const int* __restrict__ bsum, int* __restrict__ boff,
                                 int* __restrict__ rowptr) {
    __shared__ int s[128];
    int t = threadIdx.x;
    int v = (t < NBLK) ? bsum[t] : 0;
    s[t] = v; __syncthreads();
    for (int off = 1; off < 128; off <<= 1) {
        int x = (t >= off) ? s[t - off] : 0;
        __syncthreads();
        s[t] += x;
        __syncthreads();
    }
    if (t < NBLK) boff[t] = s[t] - v;      // exclusive prefix
    if (t == NBLK - 1) rowptr[NN] = s[t];  // == NE
}

__global__ void scan_fill_kernel(const int* __restrict__ deg, const int* __restrict__ boff,
                                 int* __restrict__ rowptr) {
    __shared__ int part[256];
    int b = blockIdx.x, t = threadIdx.x;
    int base = b * SCAN_CHUNK + t * 4;
    int v[4];
    #pragma unroll
    for (int i = 0; i < 4; i++) { int g = base + i; v[i] = (g < NN) ? deg[g] : 0; }
    int tsum = v[0] + v[1] + v[2] + v[3];
    part[t] = tsum; __syncthreads();
    for (int off = 1; off < 256; off <<= 1) {
        int x = (t >= off) ? part[t - off] : 0;
        __syncthreads();
        part[t] += x;
        __syncthreads();
    }
    int o = boff[b] + part[t] - tsum;   // exclusive prefix for this thread
    #pragma unroll
    for (int i = 0; i < 4; i++) {
        int g = base + i;
        if (g < NN) rowptr[g] = o;
        o += v[i];
    }
}

// ---------------- CSR fill, PHYSICAL-XCD-partitioned by dst range ----------------
// Each block reads its real XCD id (HW_REG_XCC_ID) and serves the dst range
// owned by that XCD, so the 1.6 MB col slice is written by exactly ONE L2 and
// each line accumulates all its scattered 4B writes before a single writeback.
// Work is pulled off a per-XCD atomic ticket (chunks of the edge stream);
// after a range is drained, blocks steal from other ranges so completion never
// depends on the dispatch->XCD mapping.
#define FILL_CHUNK4 2048                            // int4 elements per ticket
#define FILL_NCHUNK ((NE / 4 + FILL_CHUNK4 - 1) / FILL_CHUNK4)   // 391

__global__ void __launch_bounds__(256) fill_csr_kernel(
    const int* __restrict__ src, const int* __restrict__ dst,
    const int* __restrict__ rowptr, int* __restrict__ cursor,
    int* __restrict__ col, int* __restrict__ ticket) {
    int xcd;
    asm volatile("s_getreg_b32 %0, hwreg(HW_REG_XCC_ID)" : "=s"(xcd));
    xcd &= 7;
    __shared__ int chunk_s;
    const v4i* dst4 = (const v4i*)dst;
    const v4i* src4 = (const v4i*)src;
    const int NE4 = NE / 4;
    for (int rr = 0; rr < NRANGE; rr++) {
        int r = (xcd + rr) & 7;
        int lo = r * RANGE_W, hi = lo + RANGE_W;
        for (;;) {
            __syncthreads();
            if (threadIdx.x == 0) chunk_s = atomicAdd(&ticket[r], 1);
            __syncthreads();
            int base = chunk_s * FILL_CHUNK4;
            if (base >= NE4) break;                 // uniform exit
            #pragma unroll 1
            for (int ii = 0; ii < FILL_CHUNK4 / 256; ii++) {
                int i = base + ii * 256 + threadIdx.x;
                if (i >= NE4) break;
                v4i d4 = __builtin_nontemporal_load(dst4 + i);
                v4i s4 = __builtin_nontemporal_load(src4 + i);
                #pragma unroll
                for (int k = 0; k < 4; k++) {
                    int d = d4[k];
                    if (d >= lo && d < hi) {
                        int slot = atomicAdd(&cursor[d], 1);
                        col[rowptr[d] + slot] = s4[k];
                    }
                }
            }
        }
    }
}

// ---------------- fused modality encoders + GCN layer-0 matmul ----------------
// Epilogue scales row n by dinv[n]: stores hs = h * dinv  (see gather).
__global__ void __launch_bounds__(256) encmm0_kernel(
    const float* __restrict__ xf, const float* __restrict__ xw, const float* __restrict__ xt,
    const float* __restrict__ Wf, const float* __restrict__ bf,
    const float* __restrict__ Ww, const float* __restrict__ bw,
    const float* __restrict__ Wt, const float* __restrict__ bt,
    const float* __restrict__ W0, const float* __restrict__ dinv,
    float* __restrict__ h) {
    __shared__ float xin[64][32];    // fire[0..7], wea[8..19], ter[20..29]
    __shared__ float xs[64][100];    // encoder outputs for current 96-half (+4 pad)
    __shared__ float ws[96][64];     // W0 rows for current half
    int t = threadIdx.x;
    int n0 = blockIdx.x * 64;

    {
        const float4* xf4 = (const float4*)xf;
        for (int i = t; i < 128; i += 256) {
            int n = i >> 1, q = i & 1;
            int gn = n0 + n;
            float4 v = make_float4(0, 0, 0, 0);
            if (gn < NN) v = xf4[(size_t)gn * 2 + q];
            *(float4*)&xin[n][q * 4] = v;
        }
        const float4* xw4 = (const float4*)xw;
        for (int i = t; i < 192; i += 256) {
            int n = i / 3, q = i - n * 3;
            int gn = n0 + n;
            float4 v = make_float4(0, 0, 0, 0);
            if (gn < NN) v = xw4[(size_t)gn * 3 + q];
            *(float4*)&xin[n][8 + q * 4] = v;
        }
        const float2* xt2 = (const float2*)xt;
        for (int i = t; i < 320; i += 256) {
            int n = i / 5, q = i - n * 5;
            int gn = n0 + n;
            float2 v = make_float2(0, 0);
            if (gn < NN) v = xt2[(size_t)gn * 5 + q];
            *(float2*)&xin[n][20 + q * 2] = v;
        }
    }

    int cg = t & 15, ng = t >> 4;
    int c0 = cg * 4;
    float4 acc[4];
    #pragma unroll
    for (int i = 0; i < 4; i++) acc[i] = make_float4(0, 0, 0, 0);

    for (int kh = 0; kh < 2; kh++) {
        __syncthreads();
        {
            const float4* W04 = (const float4*)W0;
            float4* ws4 = (float4*)&ws[0][0];
            for (int i = t; i < 1536; i += 256)
                ws4[i] = W04[(size_t)kh * 1536 + i];
        }
        for (int i = t; i < 6144; i += 256) {
            int n = i / 96, kk = i - n * 96;
            int col = kh * 96 + kk;
            float a;
            if (col < 64) {
                a = bf[col];
                #pragma unroll
                for (int k = 0; k < 8; k++) a = fmaf(xin[n][k], Wf[k * 64 + col], a);
            } else if (col < 128) {
                int c = col - 64;
                a = bw[c];
                #pragma unroll
                for (int k = 0; k < 12; k++) a = fmaf(xin[n][8 + k], Ww[k * 64 + c], a);
            } else {
                int c = col - 128;
                a = bt[c];
                #pragma unroll
                for (int k = 0; k < 10; k++) a = fmaf(xin[n][20 + k], Wt[k * 64 + c], a);
            }
            xs[n][kk] = fmaxf(a, 0.f);
        }
        __syncthreads();
        for (int k = 0; k < 96; k += 4) {
            float4 b0 = *(const float4*)&ws[k + 0][c0];
            float4 b1 = *(const float4*)&ws[k + 1][c0];
            float4 b2 = *(const float4*)&ws[k + 2][c0];
            float4 b3 = *(const float4*)&ws[k + 3][c0];
            #pragma unroll
            for (int i = 0; i < 4; i++) {
                float4 a = *(const float4*)&xs[ng * 4 + i][k];
                fma4(acc[i], a.x, b0); fma4(acc[i], a.y, b1);
                fma4(acc[i], a.z, b2); fma4(acc[i], a.w, b3);
            }
        }
    }
    float4* h4 = (float4*)h;
    #pragma unroll
    for (int i = 0; i < 4; i++) {
        int gn = n0 + ng * 4 + i;
        if (gn < NN) {
            float dn = dinv[gn];
            float4 v = acc[i];
            v.x *= dn; v.y *= dn; v.z *= dn; v.w *= dn;
            h4[(size_t)gn * 16 + cg] = v;
        }
    }
}

// ---------------- 64x64 matmul, register-blocked: h = (x @ W) * dinv[n] ----
__global__ void __launch_bounds__(256) mm64_kernel(
    const float* __restrict__ x, const float* __restrict__ W,
    const float* __restrict__ dinv, float* __restrict__ h) {
    __shared__ float xs[64][68];
    __shared__ float ws[64][64];
    int t = threadIdx.x;
    int n0 = blockIdx.x * 64;
    {
        const float4* W4 = (const float4*)W;
        float4* ws4 = (float4*)&ws[0][0];
        for (int i = t; i < 1024; i += 256) ws4[i] = W4[i];
        const float4* x4 = (const float4*)x;
        for (int i = t; i < 1024; i += 256) {
            int n = i >> 4, q = i & 15;
            int gn = n0 + n;
            float4 v = make_float4(0, 0, 0, 0);
            if (gn < NN) v = x4[(size_t)gn * 16 + q];
            *(float4*)&xs[n][q * 4] = v;
        }
    }
    __syncthreads();
    int cg = t & 15, ng = t >> 4;
    int c0 = cg * 4;
    float4 acc[4];
    #pragma unroll
    for (int i = 0; i < 4; i++) acc[i] = make_float4(0, 0, 0, 0);
    for (int k = 0; k < 64; k += 4) {
        float4 b0 = *(const float4*)&ws[k + 0][c0];
        float4 b1 = *(const float4*)&ws[k + 1][c0];
        float4 b2 = *(const float4*)&ws[k + 2][c0];
        float4 b3 = *(const float4*)&ws[k + 3][c0];
        #pragma unroll
        for (int i = 0; i < 4; i++) {
            float4 a = *(const float4*)&xs[ng * 4 + i][k];
            fma4(acc[i], a.x, b0); fma4(acc[i], a.y, b1);
            fma4(acc[i], a.z, b2); fma4(acc[i], a.w, b3);
        }
    }
    float4* h4 = (float4*)h;
    #pragma unroll
    for (int i = 0; i < 4; i++) {
        int gn = n0 + ng * 4 + i;
        if (gn < NN) {
            float dn = dinv[gn];
            float4 v = acc[i];
            v.x *= dn; v.y *= dn; v.z *= dn; v.w *= dn;
            h4[(size_t)gn * 16 + cg] = v;
        }
    }
}

// ---------------- CSR gather + finalize ----------------
// h rows are pre-scaled by dinv (hs = h*dinv), so edges are UNWEIGHTED:
//   out[i] = relu( dinv[i] * (sum_{j->i} hs[j] + hs[i]) + b ).
// Inactive edge slots use sentinel row NN, which is kept all-zero.
__global__ void __launch_bounds__(256) gather_kernel(
    const int* __restrict__ col, const int* __restrict__ rowptr,
    const float* __restrict__ dinv, const float* __restrict__ h,
    const float* __restrict__ bias, float* __restrict__ out) {
    int n = (blockIdx.x * blockDim.x + threadIdx.x) >> 6;
    int l = threadIdx.x & 63;
    if (n >= NN) return;
    int g = l >> 4;      // edge sub-slot 0..3
    int q = l & 15;      // float4 slot 0..15
    const float4* h4 = (const float4*)h;
    float4 acc = make_float4(0, 0, 0, 0);
    int r0 = rowptr[n], r1 = rowptr[n + 1];
    for (int base = r0; base < r1; base += 64) {
        int cnt = min(64, r1 - base);
        int pv = NN;                          // sentinel: zero row
        if (l < cnt) pv = __builtin_nontemporal_load(col + base + l);
        int steps = (cnt + 3) >> 2;
        int j = 0;
        for (; j + 4 <= steps; j += 4) {
            int e0 = (j + 0) * 4 + g, e1 = (j + 1) * 4 + g;
            int e2 = (j + 2) * 4 + g, e3 = (j + 3) * 4 + g;
            int s0 = __shfl(pv, e0);
            int s1 = __shfl(pv, e1);
            int s2 = __shfl(pv, e2);
            int s3 = __shfl(pv, e3);
            float4 v0 = h4[(size_t)s0 * 16 + q];
            float4 v1 = h4[(size_t)s1 * 16 + q];
            float4 v2 = h4[(size_t)s2 * 16 + q];
            float4 v3 = h4[(size_t)s3 * 16 + q];
            add4(acc, v0); add4(acc, v1);
            add4(acc, v2); add4(acc, v3);
        }
        for (; j < steps; j++) {
            int e = j * 4 + g;
            int s = __shfl(pv, e);
            float4 v = h4[(size_t)s * 16 + q];
            add4(acc, v);
        }
    }
    acc.x += __shfl_xor(acc.x, 16); acc.y += __shfl_xor(acc.y, 16);
    acc.z += __shfl_xor(acc.z, 16); acc.w += __shfl_xor(acc.w, 16);
    acc.x += __shfl_xor(acc.x, 32); acc.y += __shfl_xor(acc.y, 32);
    acc.z += __shfl_xor(acc.z, 32); acc.w += __shfl_xor(acc.w, 32);
    if (g == 0) {
        float dn = dinv[n];
        float4 hn = h4[(size_t)n * 16 + q];   // hs[n] = h[n]*dinv[n]
        float4 b4 = ((const float4*)bias)[q];
        float4 r;
        r.x = fmaxf(fmaf(dn, acc.x + hn.x, b4.x), 0.f);
        r.y = fmaxf(fmaf(dn, acc.y + hn.y, b4.y), 0.f);
        r.z = fmaxf(fmaf(dn, acc.z + hn.z, b4.z), 0.f);
        r.w = fmaxf(fmaf(dn, acc.w + hn.w, b4.w), 0.f);
        ((float4*)out)[(size_t)n * 16 + q] = r;
    }
}

// ---------------- fused output MLP ----------------
__global__ void __launch_bounds__(256) mlp_kernel(
    const float* __restrict__ x, const float* __restrict__ w1, const float* __restrict__ b1,
    const float* __restrict__ w2, const float* __restrict__ b2, float* __restrict__ out) {
    int t = threadIdx.x;
    int nl = t >> 5, j = t & 31;
    int n = blockIdx.x * 8 + nl;
    float acc = b1[j];
    if (n < NN) {
        #pragma unroll
        for (int k = 0; k < 64; k++) acc = fmaf(x[n * 64 + k], w1[k * 32 + j], acc);
    }
    float hj = fmaxf(acc, 0.f) * w2[j];
    #pragma unroll
    for (int off = 16; off; off >>= 1) hj += __shfl_down(hj, off, 32);
    if (j == 0 && n < NN) out[n] = hj + b2[0];
}

extern "C" void kernel_launch(void* const* d_in, const int* in_sizes, int n_in,
                              void* d_out, int out_size, void* d_ws, size_t ws_size,
                              hipStream_t stream) {
    const float* xf = (const float*)d_in[0];
    const float* xw = (const float*)d_in[1];
    const float* xt = (const float*)d_in[2];
    const int*   ei = (const int*)d_in[3];
    const int*   src = ei;
    const int*   dst = ei + NE;
    const float* Wf = (const float*)d_in[4];
    const float* bf = (const float*)d_in[5];
    const float* Ww = (const float*)d_in[6];
    const float* bw = (const float*)d_in[7];
    const float* Wt = (const float*)d_in[8];
    const float* bt = (const float*)d_in[9];
    const float* W0 = (const float*)d_in[10];
    const float* b0 = (const float*)d_in[11];
    const float* W1 = (const float*)d_in[12];
    const float* b1 = (const float*)d_in[13];
    const float* W2 = (const float*)d_in[14];
    const float* b2 = (const float*)d_in[15];
    const float* ow1 = (const float*)d_in[16];
    const float* ob1 = (const float*)d_in[17];
    const float* ow2 = (const float*)d_in[18];
    const float* ob2 = (const float*)d_in[19];
    float* out = (float*)d_out;

    // workspace layout (~65 MB)
    char* w = (char*)d_ws;
    float* h      = (float*)w;  w += (size_t)(NN + 1) * 64 * 4;  // 25.6 MB (+zero row)
    float* agg    = (float*)w;  w += (size_t)NN * 64 * 4;        // 25.6 MB
    int*   col    = (int*)w;    w += (size_t)NE * 4;             // 12.8 MB
    float* dinv   = (float*)w;  w += (size_t)NN * 4;
    int*   deg    = (int*)w;    w += (size_t)NN * 4;
    int*   cursor = (int*)w;    w += (size_t)NN * 4;
    int*   rowptr = (int*)w;    w += (size_t)(NN + 1) * 4;
    int*   bsum   = (int*)w;    w += (size_t)NBLK * 4;
    int*   boff   = (int*)w;    w += (size_t)NBLK * 4;
    int*   ticket = (int*)w;    w += (size_t)NRANGE * 4;

    // ---- CSR build (once; reused by all 3 layers) ----
    hipMemsetAsync(deg, 0, (size_t)NN * 4, stream);
    hipMemsetAsync(cursor, 0, (size_t)NN * 4, stream);
    hipMemsetAsync(ticket, 0, (size_t)NRANGE * 4, stream);
    hipMemsetAsync(h + (size_t)NN * 64, 0, 64 * 4, stream);   // sentinel zero row
    deg_kernel<<<(NE / 4 + 255) / 256, 256, 0, stream>>>(dst, deg);
    dinv_kernel<<<(NN + 255) / 256, 256, 0, stream>>>(deg, dinv);
    block_sum_kernel<<<NBLK, 256, 0, stream>>>(deg, bsum);
    scan_bsum_kernel<<<1, 128, 0, stream>>>(bsum, boff, rowptr);
    scan_fill_kernel<<<NBLK, 256, 0, stream>>>(deg, boff, rowptr);
    fill_csr_kernel<<<1024, 256, 0, stream>>>(src, dst, rowptr, cursor, col, ticket);

    // ---- layer 0: fused encoders + matmul (scaled), then gather+finalize ----
    encmm0_kernel<<<(NN + 63) / 64, 256, 0, stream>>>(xf, xw, xt, Wf, bf, Ww, bw, Wt, bt, W0, dinv, h);
    gather_kernel<<<(NN * 64 + 255) / 256, 256, 0, stream>>>(col, rowptr, dinv, h, b0, agg);

    // ---- layer 1 ----
    mm64_kernel<<<(NN + 63) / 64, 256, 0, stream>>>(agg, W1, dinv, h);
    gather_kernel<<<(NN * 64 + 255) / 256, 256, 0, stream>>>(col, rowptr, dinv, h, b1, agg);

    // ---- layer 2 ----
    mm64_kernel<<<(NN + 63) / 64, 256, 0, stream>>>(agg, W2, dinv, h);
    gather_kernel<<<(NN * 64 + 255) / 256, 256, 0, stream>>>(col, rowptr, dinv, h, b2, agg);

    // ---- output MLP ----
    mlp_kernel<<<(NN + 7) / 8, 256, 0, stream>>>(agg, ow1, ob1, ow2, ob2, out);
}

// Round 4
// 801.876 us; speedup vs baseline: 1.2412x; 1.2412x over previous
//
#include <hip/hip_runtime.h>

#define NN 100000
#define NE 3200000
#define HD 64
#define SCAN_CHUNK 1024
#define NBLK ((NN + SCAN_CHUNK - 1) / SCAN_CHUNK)   // 98

// two-phase CSR build
#define NBUCK 512
#define BWID 196                                    // 512*196 = 100352 >= NN
#define SLACK 7168                                  // avg 6250 + ~11 sigma
#define P1_EPB 8192                                 // edges per partition block
#define P1_GRID ((NE + P1_EPB - 1) / P1_EPB)        // 391

typedef int   v4i __attribute__((ext_vector_type(4)));
typedef int   v2i __attribute__((ext_vector_type(2)));
typedef float v4f __attribute__((ext_vector_type(4)));

__device__ __forceinline__ void fma4(float4& a, float s, const float4& b) {
    a.x = fmaf(s, b.x, a.x); a.y = fmaf(s, b.y, a.y);
    a.z = fmaf(s, b.z, a.z); a.w = fmaf(s, b.w, a.w);
}
__device__ __forceinline__ void add4(float4& a, const float4& b) {
    a.x += b.x; a.y += b.y; a.z += b.z; a.w += b.w;
}

__global__ void dinv_kernel(const int* __restrict__ deg, float* __restrict__ dinv) {
    int i = blockIdx.x * blockDim.x + threadIdx.x;
    if (i < NN) dinv[i] = 1.0f / sqrtf((float)(deg[i] + 1)); // +1 self-loop
}

// ---------------- prefix scan (3 kernels) ----------------
__global__ void block_sum_kernel(const int* __restrict__ deg, int* __restrict__ bsum) {
    __shared__ int red[256];
    int b = blockIdx.x, t = threadIdx.x;
    int base = b * SCAN_CHUNK + t * 4;
    int s = 0;
    #pragma unroll
    for (int i = 0; i < 4; i++) { int g = base + i; if (g < NN) s += deg[g]; }
    red[t] = s; __syncthreads();
    for (int off = 128; off > 0; off >>= 1) {
        if (t < off) red[t] += red[t + off];
        __syncthreads();
    }
    if (t == 0) bsum[b] = red[0];
}

// parallel 128-thread scan over NBLK (=98) block sums
__global__ void scan_bsum_kernel(const int* __restrict__ bsum, int* __restrict__ boff,
                                 int* __restrict__ rowptr) {
    __shared__ int s[128];
    int t = threadIdx.x;
    int v = (t < NBLK) ? bsum[t] : 0;
    s[t] = v; __syncthreads();
    for (int off = 1; off < 128; off <<= 1) {
        int x = (t >= off) ? s[t - off] : 0;
        __syncthreads();
        s[t] += x;
        __syncthreads();
    }
    if (t < NBLK) boff[t] = s[t] - v;      // exclusive prefix
    if (t == NBLK - 1) rowptr[NN] = s[t];  // == NE
}

__global__ void scan_fill_kernel(const int* __restrict__ deg, const int* __restrict__ boff,
                                 int* __restrict__ rowptr) {
    __shared__ int part[256];
    int b = blockIdx.x, t = threadIdx.x;
    int base = b * SCAN_CHUNK + t * 4;
    int v[4];
    #pragma unroll
    for (int i = 0; i < 4; i++) { int g = base + i; v[i] = (g < NN) ? deg[g] : 0; }
    int tsum = v[0] + v[1] + v[2] + v[3];
    part[t] = tsum; __syncthreads();
    for (int off = 1; off < 256; off <<= 1) {
        int x = (t >= off) ? part[t - off] : 0;
        __syncthreads();
        part[t] += x;
        __syncthreads();
    }
    int o = boff[b] + part[t] - tsum;   // exclusive prefix for this thread
    #pragma unroll
    for (int i = 0; i < 4; i++) {
        int g = base + i;
        if (g < NN) rowptr[g] = o;
        o += v[i];
    }
}

// ---------------- phase 1: bucket partition (+ degree histogram) ----------------
// Each block: 8192 edges. LDS histogram over 512 dst-buckets -> one global
// atomicAdd per bucket reserves a contiguous run in that bucket's pair region
// -> pair writes land in ~16-pair (128 B) runs: near-coalesced, no 10x
// partial-line writeback amplification. deg[] atomics folded into same pass.
__global__ void __launch_bounds__(256) partition_kernel(
    const int* __restrict__ src, const int* __restrict__ dst,
    int* __restrict__ deg, int* __restrict__ bcur, v2i* __restrict__ pairs) {
    __shared__ int hist[NBUCK];
    __shared__ int gbase[NBUCK];
    __shared__ int lofs[NBUCK];
    int t = threadIdx.x;
    for (int i = t; i < NBUCK; i += 256) { hist[i] = 0; lofs[i] = 0; }
    __syncthreads();
    const v4i* d4p = (const v4i*)dst;
    const v4i* s4p = (const v4i*)src;
    const int NE4 = NE / 4;
    int base4 = blockIdx.x * (P1_EPB / 4);
    v4i dv[8], sv[8];
    #pragma unroll
    for (int j = 0; j < 8; j++) {
        int i = base4 + j * 256 + t;
        if (i < NE4) {
            dv[j] = __builtin_nontemporal_load(d4p + i);
            sv[j] = __builtin_nontemporal_load(s4p + i);
        } else {
            dv[j] = (v4i){-1, -1, -1, -1};
            sv[j] = (v4i){0, 0, 0, 0};
        }
    }
    #pragma unroll
    for (int j = 0; j < 8; j++) {
        #pragma unroll
        for (int k = 0; k < 4; k++) {
            int d = dv[j][k];
            if (d >= 0) {
                atomicAdd(&deg[d], 1);
                atomicAdd(&hist[(unsigned)d / BWID], 1);
            }
        }
    }
    __syncthreads();
    for (int i = t; i < NBUCK; i += 256) {
        int c = hist[i];
        gbase[i] = c ? atomicAdd(&bcur[i], c) : 0;
    }
    __syncthreads();
    #pragma unroll
    for (int j = 0; j < 8; j++) {
        #pragma unroll
        for (int k = 0; k < 4; k++) {
            int d = dv[j][k];
            if (d >= 0) {
                int b = (unsigned)d / BWID;
                int o = gbase[b] + atomicAdd(&lofs[b], 1);
                if (o < SLACK) {
                    v2i p; p[0] = sv[j][k]; p[1] = d;
                    pairs[(size_t)b * SLACK + o] = p;
                }
            }
        }
    }
}

// ---------------- phase 2: per-bucket LDS scatter -> coalesced col write -----
// One block per bucket. The bucket's col slice (~25 KB) is built entirely in
// LDS (scatter there is line-granularity-free), then streamed out contiguous.
__global__ void __launch_bounds__(256) csr_fill_kernel(
    const v2i* __restrict__ pairs, const int* __restrict__ bcnt,
    const int* __restrict__ rowptr, int* __restrict__ col) {
    __shared__ int rp[BWID];
    __shared__ int cur[BWID];
    __shared__ int cols[SLACK];
    int b = blockIdx.x, t = threadIdx.x;
    int lo = b * BWID;
    if (lo >= NN) return;
    int hi = min(lo + BWID, NN);
    int nw = hi - lo;
    int rowbase = rowptr[lo];
    for (int i = t; i < nw; i += 256) { rp[i] = rowptr[lo + i] - rowbase; cur[i] = 0; }
    __syncthreads();
    int np = bcnt[b];
    if (np > SLACK) np = SLACK;
    const v2i* pb = pairs + (size_t)b * SLACK;
    for (int i = t; i < np; i += 256) {
        v2i p = __builtin_nontemporal_load(pb + i);
        int li = p[1] - lo;
        int slot = atomicAdd(&cur[li], 1);
        cols[rp[li] + slot] = p[0];
    }
    __syncthreads();
    int cnt = rowptr[hi] - rowbase;
    for (int i = t; i < cnt; i += 256)
        col[rowbase + i] = cols[i];
}

// ---------------- fused modality encoders + GCN layer-0 matmul ----------------
// Epilogue scales row n by dinv[n]: stores hs = h * dinv  (see gather).
__global__ void __launch_bounds__(256) encmm0_kernel(
    const float* __restrict__ xf, const float* __restrict__ xw, const float* __restrict__ xt,
    const float* __restrict__ Wf, const float* __restrict__ bf,
    const float* __restrict__ Ww, const float* __restrict__ bw,
    const float* __restrict__ Wt, const float* __restrict__ bt,
    const float* __restrict__ W0, const float* __restrict__ dinv,
    float* __restrict__ h) {
    __shared__ float xin[64][32];    // fire[0..7], wea[8..19], ter[20..29]
    __shared__ float xs[64][100];    // encoder outputs for current 96-half (+4 pad)
    __shared__ float ws[96][64];     // W0 rows for current half
    int t = threadIdx.x;
    int n0 = blockIdx.x * 64;

    {
        const float4* xf4 = (const float4*)xf;
        for (int i = t; i < 128; i += 256) {
            int n = i >> 1, q = i & 1;
            int gn = n0 + n;
            float4 v = make_float4(0, 0, 0, 0);
            if (gn < NN) v = xf4[(size_t)gn * 2 + q];
            *(float4*)&xin[n][q * 4] = v;
        }
        const float4* xw4 = (const float4*)xw;
        for (int i = t; i < 192; i += 256) {
            int n = i / 3, q = i - n * 3;
            int gn = n0 + n;
            float4 v = make_float4(0, 0, 0, 0);
            if (gn < NN) v = xw4[(size_t)gn * 3 + q];
            *(float4*)&xin[n][8 + q * 4] = v;
        }
        const float2* xt2 = (const float2*)xt;
        for (int i = t; i < 320; i += 256) {
            int n = i / 5, q = i - n * 5;
            int gn = n0 + n;
            float2 v = make_float2(0, 0);
            if (gn < NN) v = xt2[(size_t)gn * 5 + q];
            *(float2*)&xin[n][20 + q * 2] = v;
        }
    }

    int cg = t & 15, ng = t >> 4;
    int c0 = cg * 4;
    float4 acc[4];
    #pragma unroll
    for (int i = 0; i < 4; i++) acc[i] = make_float4(0, 0, 0, 0);

    for (int kh = 0; kh < 2; kh++) {
        __syncthreads();
        {
            const float4* W04 = (const float4*)W0;
            float4* ws4 = (float4*)&ws[0][0];
            for (int i = t; i < 1536; i += 256)
                ws4[i] = W04[(size_t)kh * 1536 + i];
        }
        for (int i = t; i < 6144; i += 256) {
            int n = i / 96, kk = i - n * 96;
            int col = kh * 96 + kk;
            float a;
            if (col < 64) {
                a = bf[col];
                #pragma unroll
                for (int k = 0; k < 8; k++) a = fmaf(xin[n][k], Wf[k * 64 + col], a);
            } else if (col < 128) {
                int c = col - 64;
                a = bw[c];
                #pragma unroll
                for (int k = 0; k < 12; k++) a = fmaf(xin[n][8 + k], Ww[k * 64 + c], a);
            } else {
                int c = col - 128;
                a = bt[c];
                #pragma unroll
                for (int k = 0; k < 10; k++) a = fmaf(xin[n][20 + k], Wt[k * 64 + c], a);
            }
            xs[n][kk] = fmaxf(a, 0.f);
        }
        __syncthreads();
        for (int k = 0; k < 96; k += 4) {
            float4 b0 = *(const float4*)&ws[k + 0][c0];
            float4 b1 = *(const float4*)&ws[k + 1][c0];
            float4 b2 = *(const float4*)&ws[k + 2][c0];
            float4 b3 = *(const float4*)&ws[k + 3][c0];
            #pragma unroll
            for (int i = 0; i < 4; i++) {
                float4 a = *(const float4*)&xs[ng * 4 + i][k];
                fma4(acc[i], a.x, b0); fma4(acc[i], a.y, b1);
                fma4(acc[i], a.z, b2); fma4(acc[i], a.w, b3);
            }
        }
    }
    float4* h4 = (float4*)h;
    #pragma unroll
    for (int i = 0; i < 4; i++) {
        int gn = n0 + ng * 4 + i;
        if (gn < NN) {
            float dn = dinv[gn];
            float4 v = acc[i];
            v.x *= dn; v.y *= dn; v.z *= dn; v.w *= dn;
            h4[(size_t)gn * 16 + cg] = v;
        }
    }
}

// ---------------- 64x64 matmul, register-blocked: h = (x @ W) * dinv[n] ----
__global__ void __launch_bounds__(256) mm64_kernel(
    const float* __restrict__ x, const float* __restrict__ W,
    const float* __restrict__ dinv, float* __restrict__ h) {
    __shared__ float xs[64][68];
    __shared__ float ws[64][64];
    int t = threadIdx.x;
    int n0 = blockIdx.x * 64;
    {
        const float4* W4 = (const float4*)W;
        float4* ws4 = (float4*)&ws[0][0];
        for (int i = t; i < 1024; i += 256) ws4[i] = W4[i];
        const float4* x4 = (const float4*)x;
        for (int i = t; i < 1024; i += 256) {
            int n = i >> 4, q = i & 15;
            int gn = n0 + n;
            float4 v = make_float4(0, 0, 0, 0);
            if (gn < NN) v = x4[(size_t)gn * 16 + q];
            *(float4*)&xs[n][q * 4] = v;
        }
    }
    __syncthreads();
    int cg = t & 15, ng = t >> 4;
    int c0 = cg * 4;
    float4 acc[4];
    #pragma unroll
    for (int i = 0; i < 4; i++) acc[i] = make_float4(0, 0, 0, 0);
    for (int k = 0; k < 64; k += 4) {
        float4 b0 = *(const float4*)&ws[k + 0][c0];
        float4 b1 = *(const float4*)&ws[k + 1][c0];
        float4 b2 = *(const float4*)&ws[k + 2][c0];
        float4 b3 = *(const float4*)&ws[k + 3][c0];
        #pragma unroll
        for (int i = 0; i < 4; i++) {
            float4 a = *(const float4*)&xs[ng * 4 + i][k];
            fma4(acc[i], a.x, b0); fma4(acc[i], a.y, b1);
            fma4(acc[i], a.z, b2); fma4(acc[i], a.w, b3);
        }
    }
    float4* h4 = (float4*)h;
    #pragma unroll
    for (int i = 0; i < 4; i++) {
        int gn = n0 + ng * 4 + i;
        if (gn < NN) {
            float dn = dinv[gn];
            float4 v = acc[i];
            v.x *= dn; v.y *= dn; v.z *= dn; v.w *= dn;
            h4[(size_t)gn * 16 + cg] = v;
        }
    }
}

// ---------------- CSR gather + finalize ----------------
// h rows are pre-scaled by dinv (hs = h*dinv), so edges are UNWEIGHTED:
//   out[i] = relu( dinv[i] * (sum_{j->i} hs[j] + hs[i]) + b ).
// Inactive edge slots use sentinel row NN, which is kept all-zero.
__global__ void __launch_bounds__(256) gather_kernel(
    const int* __restrict__ col, const int* __restrict__ rowptr,
    const float* __restrict__ dinv, const float* __restrict__ h,
    const float* __restrict__ bias, float* __restrict__ out) {
    int n = (blockIdx.x * blockDim.x + threadIdx.x) >> 6;
    int l = threadIdx.x & 63;
    if (n >= NN) return;
    int g = l >> 4;      // edge sub-slot 0..3
    int q = l & 15;      // float4 slot 0..15
    const float4* h4 = (const float4*)h;
    float4 acc = make_float4(0, 0, 0, 0);
    int r0 = rowptr[n], r1 = rowptr[n + 1];
    for (int base = r0; base < r1; base += 64) {
        int cnt = min(64, r1 - base);
        int pv = NN;                          // sentinel: zero row
        if (l < cnt) pv = __builtin_nontemporal_load(col + base + l);
        int steps = (cnt + 3) >> 2;
        int j = 0;
        for (; j + 4 <= steps; j += 4) {
            int e0 = (j + 0) * 4 + g, e1 = (j + 1) * 4 + g;
            int e2 = (j + 2) * 4 + g, e3 = (j + 3) * 4 + g;
            int s0 = __shfl(pv, e0);
            int s1 = __shfl(pv, e1);
            int s2 = __shfl(pv, e2);
            int s3 = __shfl(pv, e3);
            float4 v0 = h4[(size_t)s0 * 16 + q];
            float4 v1 = h4[(size_t)s1 * 16 + q];
            float4 v2 = h4[(size_t)s2 * 16 + q];
            float4 v3 = h4[(size_t)s3 * 16 + q];
            add4(acc, v0); add4(acc, v1);
            add4(acc, v2); add4(acc, v3);
        }
        for (; j < steps; j++) {
            int e = j * 4 + g;
            int s = __shfl(pv, e);
            float4 v = h4[(size_t)s * 16 + q];
            add4(acc, v);
        }
    }
    acc.x += __shfl_xor(acc.x, 16); acc.y += __shfl_xor(acc.y, 16);
    acc.z += __shfl_xor(acc.z, 16); acc.w += __shfl_xor(acc.w, 16);
    acc.x += __shfl_xor(acc.x, 32); acc.y += __shfl_xor(acc.y, 32);
    acc.z += __shfl_xor(acc.z, 32); acc.w += __shfl_xor(acc.w, 32);
    if (g == 0) {
        float dn = dinv[n];
        float4 hn = h4[(size_t)n * 16 + q];   // hs[n] = h[n]*dinv[n]
        float4 b4 = ((const float4*)bias)[q];
        float4 r;
        r.x = fmaxf(fmaf(dn, acc.x + hn.x, b4.x), 0.f);
        r.y = fmaxf(fmaf(dn, acc.y + hn.y, b4.y), 0.f);
        r.z = fmaxf(fmaf(dn, acc.z + hn.z, b4.z), 0.f);
        r.w = fmaxf(fmaf(dn, acc.w + hn.w, b4.w), 0.f);
        ((float4*)out)[(size_t)n * 16 + q] = r;
    }
}

// ---------------- fused output MLP ----------------
__global__ void __launch_bounds__(256) mlp_kernel(
    const float* __restrict__ x, const float* __restrict__ w1, const float* __restrict__ b1,
    const float* __restrict__ w2, const float* __restrict__ b2, float* __restrict__ out) {
    int t = threadIdx.x;
    int nl = t >> 5, j = t & 31;
    int n = blockIdx.x * 8 + nl;
    float acc = b1[j];
    if (n < NN) {
        #pragma unroll
        for (int k = 0; k < 64; k++) acc = fmaf(x[n * 64 + k], w1[k * 32 + j], acc);
    }
    float hj = fmaxf(acc, 0.f) * w2[j];
    #pragma unroll
    for (int off = 16; off; off >>= 1) hj += __shfl_down(hj, off, 32);
    if (j == 0 && n < NN) out[n] = hj + b2[0];
}

extern "C" void kernel_launch(void* const* d_in, const int* in_sizes, int n_in,
                              void* d_out, int out_size, void* d_ws, size_t ws_size,
                              hipStream_t stream) {
    const float* xf = (const float*)d_in[0];
    const float* xw = (const float*)d_in[1];
    const float* xt = (const float*)d_in[2];
    const int*   ei = (const int*)d_in[3];
    const int*   src = ei;
    const int*   dst = ei + NE;
    const float* Wf = (const float*)d_in[4];
    const float* bf = (const float*)d_in[5];
    const float* Ww = (const float*)d_in[6];
    const float* bw = (const float*)d_in[7];
    const float* Wt = (const float*)d_in[8];
    const float* bt = (const float*)d_in[9];
    const float* W0 = (const float*)d_in[10];
    const float* b0 = (const float*)d_in[11];
    const float* W1 = (const float*)d_in[12];
    const float* b1 = (const float*)d_in[13];
    const float* W2 = (const float*)d_in[14];
    const float* b2 = (const float*)d_in[15];
    const float* ow1 = (const float*)d_in[16];
    const float* ob1 = (const float*)d_in[17];
    const float* ow2 = (const float*)d_in[18];
    const float* ob2 = (const float*)d_in[19];
    float* out = (float*)d_out;

    // workspace layout (~94 MB)
    char* w = (char*)d_ws;
    float* h      = (float*)w;  w += (size_t)(NN + 1) * 64 * 4;      // 25.6 MB (+zero row)
    float* agg    = (float*)w;  w += (size_t)NN * 64 * 4;            // 25.6 MB
    int*   col    = (int*)w;    w += (size_t)NE * 4;                 // 12.8 MB
    v2i*   pairs  = (v2i*)w;    w += (size_t)NBUCK * SLACK * 8;      // 29.4 MB
    float* dinv   = (float*)w;  w += (size_t)NN * 4;
    int*   deg    = (int*)w;    w += (size_t)NN * 4;
    int*   rowptr = (int*)w;    w += (size_t)(NN + 1) * 4;
    int*   bsum   = (int*)w;    w += (size_t)NBLK * 4;
    int*   boff   = (int*)w;    w += (size_t)NBLK * 4;
    int*   bcur   = (int*)w;    w += (size_t)NBUCK * 4;

    // ---- CSR build (two-phase partition; reused by all 3 layers) ----
    hipMemsetAsync(deg, 0, (size_t)NN * 4, stream);
    hipMemsetAsync(bcur, 0, (size_t)NBUCK * 4, stream);
    hipMemsetAsync(h + (size_t)NN * 64, 0, 64 * 4, stream);   // sentinel zero row
    partition_kernel<<<P1_GRID, 256, 0, stream>>>(src, dst, deg, bcur, pairs);
    dinv_kernel<<<(NN + 255) / 256, 256, 0, stream>>>(deg, dinv);
    block_sum_kernel<<<NBLK, 256, 0, stream>>>(deg, bsum);
    scan_bsum_kernel<<<1, 128, 0, stream>>>(bsum, boff, rowptr);
    scan_fill_kernel<<<NBLK, 256, 0, stream>>>(deg, boff, rowptr);
    csr_fill_kernel<<<NBUCK, 256, 0, stream>>>(pairs, bcur, rowptr, col);

    // ---- layer 0: fused encoders + matmul (scaled), then gather+finalize ----
    encmm0_kernel<<<(NN + 63) / 64, 256, 0, stream>>>(xf, xw, xt, Wf, bf, Ww, bw, Wt, bt, W0, dinv, h);
    gather_kernel<<<(NN * 64 + 255) / 256, 256, 0, stream>>>(col, rowptr, dinv, h, b0, agg);

    // ---- layer 1 ----
    mm64_kernel<<<(NN + 63) / 64, 256, 0, stream>>>(agg, W1, dinv, h);
    gather_kernel<<<(NN * 64 + 255) / 256, 256, 0, stream>>>(col, rowptr, dinv, h, b1, agg);

    // ---- layer 2 ----
    mm64_kernel<<<(NN + 63) / 64, 256, 0, stream>>>(agg, W2, dinv, h);
    gather_kernel<<<(NN * 64 + 255) / 256, 256, 0, stream>>>(col, rowptr, dinv, h, b2, agg);

    // ---- output MLP ----
    mlp_kernel<<<(NN + 7) / 8, 256, 0, stream>>>(agg, ow1, ob1, ow2, ob2, out);
}